// Round 4
// baseline (418.510 us; speedup 1.0000x reference)
//
#include <hip/hip_runtime.h>
#include <hip/hip_fp16.h>

#define NPTS 500000
#define RPLANE 128
#define FDIM 32
#define PLSZ (RPLANE * RPLANE * FDIM)

typedef __bf16 bfx8 __attribute__((ext_vector_type(8)));
typedef float f32x4 __attribute__((ext_vector_type(4)));

struct U8 { unsigned short s[8]; };

__device__ __forceinline__ unsigned short f2bf(float f) {
    unsigned int u = __builtin_bit_cast(unsigned int, f);
    unsigned int r = (u + 0x7FFFu + ((u >> 16) & 1u)) >> 16;
    return (unsigned short)r;
}

__device__ __forceinline__ bfx8 ld_frag_g(const unsigned short* p) {
    uint4 raw = *(const uint4*)p;
    return __builtin_bit_cast(bfx8, raw);
}

__device__ __forceinline__ __half2 u2h(unsigned u) {
    return __builtin_bit_cast(__half2, u);
}

// One prep kernel: repack all 3 weight mats to bf16 MFMA-B frags + convert planes to fp16.
// Frag layout: block b = ct*(K/32)+ks holds lane l elems j: B[ks*32+(l>>4)*8+j][ct*16+(l&15)].
__global__ void prep_all(const float* __restrict__ wenc, const float* __restrict__ w1,
                         const float* __restrict__ w2, const float* __restrict__ spf,
                         const float* __restrict__ tpf,
                         unsigned short* __restrict__ wf, __half* __restrict__ ph) {
    const int WTOT = 86016;
    const int PTOT = 6 * PLSZ;
    const int total = WTOT + PTOT;
    for (int i = blockIdx.x * blockDim.x + threadIdx.x; i < total;
         i += gridDim.x * blockDim.x) {
        if (i < WTOT) {
            const float* W;
            unsigned short* dst;
            int K, Ncols, idx;
            if (i < 8192)       { W = wenc; K = 32;  Ncols = 256; idx = i;         dst = wf; }
            else if (i < 73728) { W = w1;   K = 256; Ncols = 256; idx = i - 8192;  dst = wf + 8192; }
            else                { W = w2;   K = 256; Ncols = 48;  idx = i - 73728; dst = wf + 73728; }
            int j = idx & 7;
            int l = (idx >> 3) & 63;
            int b = idx >> 9;
            int KS = K >> 5;
            int ct = b / KS;
            int ks = b - ct * KS;
            int k = ks * 32 + ((l >> 4) << 3) + j;
            int col = ct * 16 + (l & 15);
            dst[idx] = f2bf(W[(size_t)k * Ncols + col]);
        } else {
            int j = i - WTOT;
            float v = (j < 3 * PLSZ) ? spf[j] : tpf[j - 3 * PLSZ];
            ph[j] = __float2half(v);
        }
    }
}

// Passthrough outputs: out[0:3N)=rays, out[3N:7N)=rot, out[7N:8N)=h_emb[:,0]
__global__ void pass_copy(const float* __restrict__ rays, const float* __restrict__ rot,
                          const float* __restrict__ h, float* __restrict__ out) {
    const int total = NPTS * 8;
    for (int i = blockIdx.x * blockDim.x + threadIdx.x; i < total; i += gridDim.x * blockDim.x) {
        float v;
        if (i < NPTS * 3) v = rays[i];
        else if (i < NPTS * 7) v = rot[i - NPTS * 3];
        else v = h[(i - NPTS * 7) * 2];
        out[i] = v;
    }
}

// Wave-synchronous: 16 points per wave, gather direct to A-frag registers,
// single swizzled h-buffer per wave, no barriers.
__global__ __launch_bounds__(256, 4) void fused3(
    const float* __restrict__ rays, const float* __restrict__ tme,
    const float* __restrict__ shs, const __half* __restrict__ ph,
    const unsigned short* __restrict__ wf,
    const float* __restrict__ benc, const float* __restrict__ b1v,
    const float* __restrict__ b2v, float* __restrict__ out) {
    __shared__ unsigned short hbuf[4][16 * 256];   // per-wave [16 pts][256], XOR-swizzled
    const int tid = threadIdx.x;
    const int wid = tid >> 6;
    const int lane = tid & 63;
    const int p0 = blockIdx.x * 64 + wid * 16;
    if (p0 >= NPTS) return;
    char* hw = (char*)hbuf[wid];

    const int lrow = lane & 15;            // point row within tile / D col
    const int lg = lane >> 4;              // lane group 0..3
    const int drow = lg << 2;              // D row base
    const int pt = p0 + lrow;
    const int f0 = lg << 3;                // this lane's 8-feature slice

    // ---- gather: bilinear-sample 6 fp16 planes, product, -> A-frag regs ----
    float px = rays[pt * 3 + 0], py = rays[pt * 3 + 1], pz = rays[pt * 3 + 2];
    const float inv = 0.625f;
    float xn = fminf(fmaxf(px * inv, -1.f), 1.f) * 0.5f + 0.5f;
    float yn = fminf(fmaxf(py * inv, -1.f), 1.f) * 0.5f + 0.5f;
    float zn = fminf(fmaxf(pz * inv, -1.f), 1.f) * 0.5f + 0.5f;
    float tt = fminf(fmaxf(tme[pt], 0.f), 1.f);

    // decompose each of 4 coords once
    float c4[4] = {xn, yn, zn, tt};
    int i0[4];
    float fr[4];
#pragma unroll
    for (int c = 0; c < 4; ++c) {
        float x = c4[c] * 127.0f;
        float xf = fminf(floorf(x), 126.0f);
        i0[c] = (int)xf;
        fr[c] = x - xf;
    }
    // plane -> (u-coord idx, v-coord idx): s0(x,y) s1(x,z) s2(y,z) t0(x,t) t1(y,t) t2(z,t)
    const int uc[6] = {0, 0, 1, 0, 1, 2};
    const int vc[6] = {1, 2, 2, 3, 3, 3};

    __half2 g2[4];
#pragma unroll
    for (int pl = 0; pl < 6; ++pl) {
        int x0 = i0[uc[pl]], y0 = i0[vc[pl]];
        float fx = fr[uc[pl]], fy = fr[vc[pl]];
        const __half* base = ph + (size_t)pl * PLSZ + ((y0 * RPLANE + x0) << 5) + f0;
        uint4 q00 = *(const uint4*)base;
        uint4 q01 = *(const uint4*)(base + FDIM);
        uint4 q10 = *(const uint4*)(base + RPLANE * FDIM);
        uint4 q11 = *(const uint4*)(base + RPLANE * FDIM + FDIM);
        __half2 wa = __float2half2_rn((1.f - fx) * (1.f - fy));
        __half2 wb = __float2half2_rn(fx * (1.f - fy));
        __half2 wc = __float2half2_rn((1.f - fx) * fy);
        __half2 wd = __float2half2_rn(fx * fy);
        unsigned qa[4] = {q00.x, q00.y, q00.z, q00.w};
        unsigned qb[4] = {q01.x, q01.y, q01.z, q01.w};
        unsigned qc[4] = {q10.x, q10.y, q10.z, q10.w};
        unsigned qd[4] = {q11.x, q11.y, q11.z, q11.w};
#pragma unroll
        for (int i = 0; i < 4; ++i) {
            __half2 r = __hmul2(u2h(qa[i]), wa);
            r = __hfma2(u2h(qb[i]), wb, r);
            r = __hfma2(u2h(qc[i]), wc, r);
            r = __hfma2(u2h(qd[i]), wd, r);
            g2[i] = (pl == 0) ? r : __hmul2(g2[i], r);
        }
    }
    U8 af;
#pragma unroll
    for (int i = 0; i < 4; ++i) {
        float2 v = __half22float2(g2[i]);
        af.s[2 * i] = f2bf(v.x);
        af.s[2 * i + 1] = f2bf(v.y);
    }
    bfx8 a1 = __builtin_bit_cast(bfx8, af);

    // swizzled LDS helpers: byte = row*512 + col*2, ^ (row&7)<<4
    // ---- layer 1: [16,32] @ [32,256] + b_enc, relu -> hw ----
#pragma unroll
    for (int ct = 0; ct < 16; ++ct) {
        bfx8 b = ld_frag_g(wf + (size_t)ct * 512 + lane * 8);
        f32x4 z = {0.f, 0.f, 0.f, 0.f};
        f32x4 d = __builtin_amdgcn_mfma_f32_16x16x32_bf16(a1, b, z, 0, 0, 0);
        float bias = benc[ct * 16 + lrow];
#pragma unroll
        for (int r = 0; r < 4; ++r) {
            int row = drow + r;
            int off = ((row << 9) + (ct << 5) + (lrow << 1)) ^ ((row & 7) << 4);
            *(unsigned short*)(hw + off) = f2bf(fmaxf(d[r] + bias, 0.f));
        }
    }

    // ---- layer 2: [16,256] @ [256,256] + b1, relu -> hw in place ----
    const unsigned short* w1f = wf + 8192;
    bfx8 A2[8];
#pragma unroll
    for (int ks = 0; ks < 8; ++ks) {
        int off = ((lrow << 9) + (ks << 6) + (lg << 4)) ^ ((lrow & 7) << 4);
        A2[ks] = __builtin_bit_cast(bfx8, *(uint4*)(hw + off));
    }
#pragma unroll
    for (int ct = 0; ct < 16; ++ct) {
        f32x4 acc = {0.f, 0.f, 0.f, 0.f};
#pragma unroll
        for (int ks = 0; ks < 8; ++ks) {
            bfx8 B = ld_frag_g(w1f + (size_t)(ct * 8 + ks) * 512 + lane * 8);
            acc = __builtin_amdgcn_mfma_f32_16x16x32_bf16(A2[ks], B, acc, 0, 0, 0);
        }
        float bias = b1v[ct * 16 + lrow];
#pragma unroll
        for (int r = 0; r < 4; ++r) {
            int row = drow + r;
            int off = ((row << 9) + (ct << 5) + (lrow << 1)) ^ ((row & 7) << 4);
            *(unsigned short*)(hw + off) = f2bf(fmaxf(acc[r] + bias, 0.f));
        }
    }

    // ---- layer 3: [16,256] @ [256,48] + b2 + shs -> out ----
    const unsigned short* w2f = wf + 73728;
    bfx8 A3[8];
#pragma unroll
    for (int ks = 0; ks < 8; ++ks) {
        int off = ((lrow << 9) + (ks << 6) + (lg << 4)) ^ ((lrow & 7) << 4);
        A3[ks] = __builtin_bit_cast(bfx8, *(uint4*)(hw + off));
    }
#pragma unroll
    for (int ct = 0; ct < 3; ++ct) {
        f32x4 acc = {0.f, 0.f, 0.f, 0.f};
#pragma unroll
        for (int ks = 0; ks < 8; ++ks) {
            bfx8 B = ld_frag_g(w2f + (size_t)(ct * 8 + ks) * 512 + lane * 8);
            acc = __builtin_amdgcn_mfma_f32_16x16x32_bf16(A3[ks], B, acc, 0, 0, 0);
        }
        int col = ct * 16 + lrow;
        float bias = b2v[col];
#pragma unroll
        for (int r = 0; r < 4; ++r) {
            int pr = p0 + drow + r;
            out[(size_t)NPTS * 8 + (size_t)pr * 48 + col] =
                shs[(size_t)pr * 48 + col] + acc[r] + bias;
        }
    }
}

extern "C" void kernel_launch(void* const* d_in, const int* in_sizes, int n_in,
                              void* d_out, int out_size, void* d_ws, size_t ws_size,
                              hipStream_t stream) {
    const float* rays = (const float*)d_in[0];
    const float* rot  = (const float*)d_in[1];
    const float* shs  = (const float*)d_in[3];
    const float* tme  = (const float*)d_in[5];
    const float* h_e  = (const float*)d_in[6];
    const float* spf  = (const float*)d_in[7];
    const float* tpf  = (const float*)d_in[8];
    const float* wenc = (const float*)d_in[9];
    const float* benc = (const float*)d_in[10];
    const float* w1   = (const float*)d_in[11];
    const float* b1v  = (const float*)d_in[12];
    const float* w2   = (const float*)d_in[13];
    const float* b2v  = (const float*)d_in[14];
    float* out = (float*)d_out;
    unsigned short* wf = (unsigned short*)d_ws;    // 86016 shorts of weight frags
    __half* ph = (__half*)(wf + 86016);            // 6*PLSZ fp16 plane cache (~6.3 MB)

    prep_all<<<3408, 256, 0, stream>>>(wenc, w1, w2, spf, tpf, wf, ph);
    pass_copy<<<2048, 256, 0, stream>>>(rays, rot, h_e, out);
    fused3<<<(NPTS + 63) / 64, 256, 0, stream>>>(
        rays, tme, shs, ph, wf, benc, b1v, b2v, out);
}

// Round 5
// 236.445 us; speedup vs baseline: 1.7700x; 1.7700x over previous
//
#include <hip/hip_runtime.h>
#include <hip/hip_fp16.h>

#define NPTS 500000
#define RPLANE 128
#define FDIM 32
#define PLSZ (RPLANE * RPLANE * FDIM)

typedef __bf16 bfx8 __attribute__((ext_vector_type(8)));
typedef float f32x4 __attribute__((ext_vector_type(4)));

__device__ __forceinline__ unsigned short f2bf(float f) {
    unsigned int u = __builtin_bit_cast(unsigned int, f);
    unsigned int r = (u + 0x7FFFu + ((u >> 16) & 1u)) >> 16;
    return (unsigned short)r;
}

__device__ __forceinline__ unsigned pk2(float a, float b) {
    return (unsigned)f2bf(a) | ((unsigned)f2bf(b) << 16);
}

__device__ __forceinline__ __half2 u2h(unsigned u) {
    return __builtin_bit_cast(__half2, u);
}

__device__ __forceinline__ bfx8 asfrag(uint4 v) {
    return __builtin_bit_cast(bfx8, v);
}

// D->act-frag conversion: from two packed D tiles (even e0,e1 / odd o0,o1),
// build one act frag (4 u32). a0/a1 are bpermute byte-addrs, sel = (lane>=32).
__device__ __forceinline__ uint4 convD(unsigned e0, unsigned e1, unsigned o0,
                                       unsigned o1, int a0, int a1, bool sel) {
    uint4 W;
    int x, y;
    x = __builtin_amdgcn_ds_bpermute(a0, (int)e0);
    y = __builtin_amdgcn_ds_bpermute(a0, (int)o0);
    W.x = (unsigned)(sel ? y : x);
    x = __builtin_amdgcn_ds_bpermute(a0, (int)e1);
    y = __builtin_amdgcn_ds_bpermute(a0, (int)o1);
    W.y = (unsigned)(sel ? y : x);
    x = __builtin_amdgcn_ds_bpermute(a1, (int)e0);
    y = __builtin_amdgcn_ds_bpermute(a1, (int)o0);
    W.z = (unsigned)(sel ? y : x);
    x = __builtin_amdgcn_ds_bpermute(a1, (int)e1);
    y = __builtin_amdgcn_ds_bpermute(a1, (int)o1);
    W.w = (unsigned)(sel ? y : x);
    return W;
}

// Repack weight mats to bf16 MFMA frags + planes to fp16.
// Frag block b = ct*(K/32)+ks, lane l, elem j: W[k=ks*32+(l>>4)*8+j][col=ct*16+(l&15)].
__global__ void prep_all(const float* __restrict__ wenc, const float* __restrict__ w1,
                         const float* __restrict__ w2, const float* __restrict__ spf,
                         const float* __restrict__ tpf,
                         unsigned short* __restrict__ wf, __half* __restrict__ ph) {
    const int WTOT = 86016;
    const int PTOT = 6 * PLSZ;
    const int total = WTOT + PTOT;
    for (int i = blockIdx.x * blockDim.x + threadIdx.x; i < total;
         i += gridDim.x * blockDim.x) {
        if (i < WTOT) {
            const float* W;
            unsigned short* dst;
            int K, Ncols, idx;
            if (i < 8192)       { W = wenc; K = 32;  Ncols = 256; idx = i;         dst = wf; }
            else if (i < 73728) { W = w1;   K = 256; Ncols = 256; idx = i - 8192;  dst = wf + 8192; }
            else                { W = w2;   K = 256; Ncols = 48;  idx = i - 73728; dst = wf + 73728; }
            int j = idx & 7;
            int l = (idx >> 3) & 63;
            int b = idx >> 9;
            int KS = K >> 5;
            int ct = b / KS;
            int ks = b - ct * KS;
            int k = ks * 32 + ((l >> 4) << 3) + j;
            int col = ct * 16 + (l & 15);
            dst[idx] = f2bf(W[(size_t)k * Ncols + col]);
        } else {
            int j = i - WTOT;
            float v = (j < 3 * PLSZ) ? spf[j] : tpf[j - 3 * PLSZ];
            ph[j] = __float2half(v);
        }
    }
}

// Passthrough outputs: out[0:3N)=rays, out[3N:7N)=rot, out[7N:8N)=h_emb[:,0]
__global__ void pass_copy(const float* __restrict__ rays, const float* __restrict__ rot,
                          const float* __restrict__ h, float* __restrict__ out) {
    const int total = NPTS * 8;
    for (int i = blockIdx.x * blockDim.x + threadIdx.x; i < total; i += gridDim.x * blockDim.x) {
        float v;
        if (i < NPTS * 3) v = rays[i];
        else if (i < NPTS * 7) v = rot[i - NPTS * 3];
        else v = h[(i - NPTS * 7) * 2];
        out[i] = v;
    }
}

// Fully register-resident fused MLP: 32 pts/wave, no LDS, no barriers.
__global__ __launch_bounds__(256, 2) void fused4(
    const float* __restrict__ rays, const float* __restrict__ tme,
    const float* __restrict__ shs, const __half* __restrict__ ph,
    const unsigned short* __restrict__ wf,
    const float* __restrict__ benc, const float* __restrict__ b1v,
    const float* __restrict__ b2v, float* __restrict__ out) {
    const int tid = threadIdx.x;
    const int wid = tid >> 6;
    const int lane = tid & 63;
    const int p0 = blockIdx.x * 128 + wid * 32;
    if (p0 >= NPTS) return;
    const int g = lane >> 4;
    const int c = lane & 15;
    const int f0 = g << 3;
    const int a0 = 4 * (32 * (g & 1) + c);   // bpermute addr: src group 2(g&1)
    const int a1 = a0 + 64;                  // src group 2(g&1)+1
    const bool sel = (g >> 1) != 0;

    // ---- gather -> act1 frags (B-layout: k=feature at 8g+j, n=point at c) ----
    bfx8 act1[2];
#pragma unroll
    for (int pt = 0; pt < 2; ++pt) {
        int p = p0 + pt * 16 + c;
        float px = rays[p * 3 + 0], py = rays[p * 3 + 1], pz = rays[p * 3 + 2];
        const float inv = 0.625f;
        float xn = fminf(fmaxf(px * inv, -1.f), 1.f) * 0.5f + 0.5f;
        float yn = fminf(fmaxf(py * inv, -1.f), 1.f) * 0.5f + 0.5f;
        float zn = fminf(fmaxf(pz * inv, -1.f), 1.f) * 0.5f + 0.5f;
        float tt = fminf(fmaxf(tme[p], 0.f), 1.f);
        float c4[4] = {xn, yn, zn, tt};
        int i0[4];
        float fr[4];
#pragma unroll
        for (int cc = 0; cc < 4; ++cc) {
            float x = c4[cc] * 127.0f;
            float xf = fminf(floorf(x), 126.0f);
            i0[cc] = (int)xf;
            fr[cc] = x - xf;
        }
        const int uc[6] = {0, 0, 1, 0, 1, 2};
        const int vc[6] = {1, 2, 2, 3, 3, 3};
        __half2 g2[4];
#pragma unroll
        for (int pl = 0; pl < 6; ++pl) {
            int x0 = i0[uc[pl]], y0 = i0[vc[pl]];
            float fx = fr[uc[pl]], fy = fr[vc[pl]];
            const __half* base = ph + (size_t)pl * PLSZ + ((y0 * RPLANE + x0) << 5) + f0;
            uint4 q00 = *(const uint4*)base;
            uint4 q01 = *(const uint4*)(base + FDIM);
            uint4 q10 = *(const uint4*)(base + RPLANE * FDIM);
            uint4 q11 = *(const uint4*)(base + RPLANE * FDIM + FDIM);
            __half2 wa = __float2half2_rn((1.f - fx) * (1.f - fy));
            __half2 wb = __float2half2_rn(fx * (1.f - fy));
            __half2 wc = __float2half2_rn((1.f - fx) * fy);
            __half2 wd = __float2half2_rn(fx * fy);
            unsigned qa[4] = {q00.x, q00.y, q00.z, q00.w};
            unsigned qb[4] = {q01.x, q01.y, q01.z, q01.w};
            unsigned qc[4] = {q10.x, q10.y, q10.z, q10.w};
            unsigned qd[4] = {q11.x, q11.y, q11.z, q11.w};
#pragma unroll
            for (int i = 0; i < 4; ++i) {
                __half2 r = __hmul2(u2h(qa[i]), wa);
                r = __hfma2(u2h(qb[i]), wb, r);
                r = __hfma2(u2h(qc[i]), wc, r);
                r = __hfma2(u2h(qd[i]), wd, r);
                g2[i] = (pl == 0) ? r : __hmul2(g2[i], r);
            }
        }
        uint4 av;
        {
            float2 v0 = __half22float2(g2[0]);
            float2 v1 = __half22float2(g2[1]);
            float2 v2 = __half22float2(g2[2]);
            float2 v3 = __half22float2(g2[3]);
            av.x = pk2(v0.x, v0.y);
            av.y = pk2(v1.x, v1.y);
            av.z = pk2(v2.x, v2.y);
            av.w = pk2(v3.x, v3.y);
        }
        act1[pt] = asfrag(av);
    }

    // ---- layer 1: D[outcol][pt] = mfma(w_enc frag, act1); relu; convert -> act2 ----
    uint4 act2[2][8];
    {
        uint4 wA = *(const uint4*)(wf + 0 * 512 + lane * 8);
        uint4 wB;
        unsigned stE[2][2];
#pragma unroll
        for (int ct = 0; ct < 16; ++ct) {
            uint4 cur = (ct & 1) ? wB : wA;
            if (ct < 15) {
                uint4 nx = *(const uint4*)(wf + (size_t)(ct + 1) * 512 + lane * 8);
                if (ct & 1) wA = nx; else wB = nx;
            }
            float4 b4 = *(const float4*)(benc + 16 * ct + 4 * g);
            float bb[4] = {b4.x, b4.y, b4.z, b4.w};
#pragma unroll
            for (int pt = 0; pt < 2; ++pt) {
                f32x4 z = {0.f, 0.f, 0.f, 0.f};
                f32x4 d = __builtin_amdgcn_mfma_f32_16x16x32_bf16(asfrag(cur), act1[pt], z, 0, 0, 0);
                float v0 = fmaxf(d[0] + bb[0], 0.f);
                float v1 = fmaxf(d[1] + bb[1], 0.f);
                float v2 = fmaxf(d[2] + bb[2], 0.f);
                float v3 = fmaxf(d[3] + bb[3], 0.f);
                unsigned Q0 = pk2(v0, v1), Q1 = pk2(v2, v3);
                if ((ct & 1) == 0) {
                    stE[pt][0] = Q0; stE[pt][1] = Q1;
                } else {
                    act2[pt][ct >> 1] = convD(stE[pt][0], stE[pt][1], Q0, Q1, a0, a1, sel);
                }
            }
        }
    }

    // ---- layer 2: 256x256; prefetched 8-frag dbuf; convert -> act3 ----
    uint4 act3[2][8];
    {
        const unsigned short* w1f = wf + 8192;
        uint4 bufA[8], bufB[8];
#pragma unroll
        for (int ks = 0; ks < 8; ++ks)
            bufA[ks] = *(const uint4*)(w1f + (size_t)ks * 512 + lane * 8);
        unsigned stE[2][2];
#pragma unroll
        for (int ct = 0; ct < 16; ++ct) {
            if (ct < 15) {
#pragma unroll
                for (int ks = 0; ks < 8; ++ks) {
                    uint4 nx = *(const uint4*)(w1f + (size_t)((ct + 1) * 8 + ks) * 512 + lane * 8);
                    if (ct & 1) bufA[ks] = nx; else bufB[ks] = nx;
                }
            }
            float4 b4 = *(const float4*)(b1v + 16 * ct + 4 * g);
            float bb[4] = {b4.x, b4.y, b4.z, b4.w};
#pragma unroll
            for (int pt = 0; pt < 2; ++pt) {
                f32x4 acc = {0.f, 0.f, 0.f, 0.f};
#pragma unroll
                for (int ks = 0; ks < 8; ++ks) {
                    uint4 w = (ct & 1) ? bufB[ks] : bufA[ks];
                    acc = __builtin_amdgcn_mfma_f32_16x16x32_bf16(asfrag(w), asfrag(act2[pt][ks]), acc, 0, 0, 0);
                }
                float v0 = fmaxf(acc[0] + bb[0], 0.f);
                float v1 = fmaxf(acc[1] + bb[1], 0.f);
                float v2 = fmaxf(acc[2] + bb[2], 0.f);
                float v3 = fmaxf(acc[3] + bb[3], 0.f);
                unsigned Q0 = pk2(v0, v1), Q1 = pk2(v2, v3);
                if ((ct & 1) == 0) {
                    stE[pt][0] = Q0; stE[pt][1] = Q1;
                } else {
                    act3[pt][ct >> 1] = convD(stE[pt][0], stE[pt][1], Q0, Q1, a0, a1, sel);
                }
            }
        }
    }

    // ---- layer 3: D[pt][outcol] = mfma(act3, w2 frag); + b2 + shs -> out ----
    {
        const unsigned short* w2f = wf + 73728;
#pragma unroll
        for (int ct = 0; ct < 3; ++ct) {
            uint4 wl[8];
#pragma unroll
            for (int ks = 0; ks < 8; ++ks)
                wl[ks] = *(const uint4*)(w2f + (size_t)(ct * 8 + ks) * 512 + lane * 8);
            float bias = b2v[16 * ct + c];
#pragma unroll
            for (int pt = 0; pt < 2; ++pt) {
                f32x4 acc = {0.f, 0.f, 0.f, 0.f};
#pragma unroll
                for (int ks = 0; ks < 8; ++ks)
                    acc = __builtin_amdgcn_mfma_f32_16x16x32_bf16(asfrag(act3[pt][ks]), asfrag(wl[ks]), acc, 0, 0, 0);
#pragma unroll
                for (int r = 0; r < 4; ++r) {
                    int p = p0 + pt * 16 + 4 * g + r;
                    size_t idx = (size_t)p * 48 + 16 * ct + c;
                    out[(size_t)NPTS * 8 + idx] = shs[idx] + acc[r] + bias;
                }
            }
        }
    }
}

extern "C" void kernel_launch(void* const* d_in, const int* in_sizes, int n_in,
                              void* d_out, int out_size, void* d_ws, size_t ws_size,
                              hipStream_t stream) {
    const float* rays = (const float*)d_in[0];
    const float* rot  = (const float*)d_in[1];
    const float* shs  = (const float*)d_in[3];
    const float* tme  = (const float*)d_in[5];
    const float* h_e  = (const float*)d_in[6];
    const float* spf  = (const float*)d_in[7];
    const float* tpf  = (const float*)d_in[8];
    const float* wenc = (const float*)d_in[9];
    const float* benc = (const float*)d_in[10];
    const float* w1   = (const float*)d_in[11];
    const float* b1v  = (const float*)d_in[12];
    const float* w2   = (const float*)d_in[13];
    const float* b2v  = (const float*)d_in[14];
    float* out = (float*)d_out;
    unsigned short* wf = (unsigned short*)d_ws;    // 86016 shorts of weight frags
    __half* ph = (__half*)(wf + 86016);            // 6*PLSZ fp16 plane cache (~6.3 MB)

    prep_all<<<3408, 256, 0, stream>>>(wenc, w1, w2, spf, tpf, wf, ph);
    pass_copy<<<2048, 256, 0, stream>>>(rays, rot, h_e, out);
    fused4<<<(NPTS + 127) / 128, 256, 0, stream>>>(
        rays, tme, shs, ph, wf, benc, b1v, b2v, out);
}

// Round 6
// 207.339 us; speedup vs baseline: 2.0185x; 1.1404x over previous
//
#include <hip/hip_runtime.h>
#include <hip/hip_fp16.h>

#define NPTS 500000
#define RPLANE 128
#define FDIM 32
#define PLSZ (RPLANE * RPLANE * FDIM)
#define NTILES 15625          // 500000 / 32
#define NBLK 977              // ceil(15625 / 16): 8 waves x 2 tiles each
#define TSTRIDE (NBLK * 8)    // 7816

typedef __bf16 bfx8 __attribute__((ext_vector_type(8)));
typedef float f32x4 __attribute__((ext_vector_type(4)));

__device__ __forceinline__ unsigned short f2bf(float f) {
    unsigned int u = __builtin_bit_cast(unsigned int, f);
    unsigned int r = (u + 0x7FFFu + ((u >> 16) & 1u)) >> 16;
    return (unsigned short)r;
}

__device__ __forceinline__ unsigned pk2(float a, float b) {
    return (unsigned)f2bf(a) | ((unsigned)f2bf(b) << 16);
}

__device__ __forceinline__ __half2 u2h(unsigned u) {
    return __builtin_bit_cast(__half2, u);
}

__device__ __forceinline__ bfx8 asfrag(uint4 v) {
    return __builtin_bit_cast(bfx8, v);
}

// D->act-frag conversion: from two packed D tiles (even e0,e1 / odd o0,o1),
// build one act frag (4 u32). a0/a1 are bpermute byte-addrs, sel = (lane>=32).
__device__ __forceinline__ uint4 convD(unsigned e0, unsigned e1, unsigned o0,
                                       unsigned o1, int a0, int a1, bool sel) {
    uint4 W;
    int x, y;
    x = __builtin_amdgcn_ds_bpermute(a0, (int)e0);
    y = __builtin_amdgcn_ds_bpermute(a0, (int)o0);
    W.x = (unsigned)(sel ? y : x);
    x = __builtin_amdgcn_ds_bpermute(a0, (int)e1);
    y = __builtin_amdgcn_ds_bpermute(a0, (int)o1);
    W.y = (unsigned)(sel ? y : x);
    x = __builtin_amdgcn_ds_bpermute(a1, (int)e0);
    y = __builtin_amdgcn_ds_bpermute(a1, (int)o0);
    W.z = (unsigned)(sel ? y : x);
    x = __builtin_amdgcn_ds_bpermute(a1, (int)e1);
    y = __builtin_amdgcn_ds_bpermute(a1, (int)o1);
    W.w = (unsigned)(sel ? y : x);
    return W;
}

// Repack weight mats to bf16 MFMA frags + planes to fp16.
// Frag block b = ct*(K/32)+ks, lane l, elem j: W[k=ks*32+(l>>4)*8+j][col=ct*16+(l&15)].
__global__ void prep_all(const float* __restrict__ wenc, const float* __restrict__ w1,
                         const float* __restrict__ w2, const float* __restrict__ spf,
                         const float* __restrict__ tpf,
                         unsigned short* __restrict__ wf, __half* __restrict__ ph) {
    const int WTOT = 86016;
    const int PTOT = 6 * PLSZ;
    const int total = WTOT + PTOT;
    for (int i = blockIdx.x * blockDim.x + threadIdx.x; i < total;
         i += gridDim.x * blockDim.x) {
        if (i < WTOT) {
            const float* W;
            unsigned short* dst;
            int K, Ncols, idx;
            if (i < 8192)       { W = wenc; K = 32;  Ncols = 256; idx = i;         dst = wf; }
            else if (i < 73728) { W = w1;   K = 256; Ncols = 256; idx = i - 8192;  dst = wf + 8192; }
            else                { W = w2;   K = 256; Ncols = 48;  idx = i - 73728; dst = wf + 73728; }
            int j = idx & 7;
            int l = (idx >> 3) & 63;
            int b = idx >> 9;
            int KS = K >> 5;
            int ct = b / KS;
            int ks = b - ct * KS;
            int k = ks * 32 + ((l >> 4) << 3) + j;
            int col = ct * 16 + (l & 15);
            dst[idx] = f2bf(W[(size_t)k * Ncols + col]);
        } else {
            int j = i - WTOT;
            float v = (j < 3 * PLSZ) ? spf[j] : tpf[j - 3 * PLSZ];
            ph[j] = __float2half(v);
        }
    }
}

// Passthrough outputs: out[0:3N)=rays, out[3N:7N)=rot, out[7N:8N)=h_emb[:,0]
__global__ void pass_copy(const float* __restrict__ rays, const float* __restrict__ rot,
                          const float* __restrict__ h, float* __restrict__ out) {
    const int total = NPTS * 8;
    for (int i = blockIdx.x * blockDim.x + threadIdx.x; i < total; i += gridDim.x * blockDim.x) {
        float v;
        if (i < NPTS * 3) v = rays[i];
        else if (i < NPTS * 7) v = rot[i - NPTS * 3];
        else v = h[(i - NPTS * 7) * 2];
        out[i] = v;
    }
}

// 8 waves/block share w1+w2 frags staged in LDS; each wave runs a fully
// register-resident 32-pt MLP pipeline for 2 tiles. One barrier total.
__global__ __launch_bounds__(512, 2) void fused5(
    const float* __restrict__ rays, const float* __restrict__ tme,
    const float* __restrict__ shs, const __half* __restrict__ ph,
    const unsigned short* __restrict__ wf,
    const float* __restrict__ benc, const float* __restrict__ b1v,
    const float* __restrict__ b2v, float* __restrict__ out) {
    __shared__ unsigned short wlds[77824];   // w1 frags [0,65536) + w2 frags [65536,77824)
    const int tid = threadIdx.x;
    const int wid = tid >> 6;
    const int lane = tid & 63;

    // ---- stage w1+w2 frags global->LDS (linear copy), one barrier ----
#pragma unroll
    for (int i = tid * 8; i < 77824; i += 512 * 8)
        *(uint4*)&wlds[i] = *(const uint4*)(wf + 8192 + i);
    __syncthreads();

    const int g = lane >> 4;
    const int c = lane & 15;
    const int f0 = g << 3;
    const int a0 = 4 * (32 * (g & 1) + c);   // bpermute addr: src group 2(g&1)
    const int a1 = a0 + 64;                  // src group 2(g&1)+1
    const bool sel = (g >> 1) != 0;

    for (int k = 0; k < 2; ++k) {
        int tile = blockIdx.x * 8 + wid + k * TSTRIDE;
        if (tile >= NTILES) continue;
        const int p0 = tile * 32;

        // ---- gather -> act1 frags (B-layout: k=feature 8g+j, n=point c) ----
        bfx8 act1[2];
#pragma unroll
        for (int pt = 0; pt < 2; ++pt) {
            int p = p0 + pt * 16 + c;
            float px = rays[p * 3 + 0], py = rays[p * 3 + 1], pz = rays[p * 3 + 2];
            const float inv = 0.625f;
            float xn = fminf(fmaxf(px * inv, -1.f), 1.f) * 0.5f + 0.5f;
            float yn = fminf(fmaxf(py * inv, -1.f), 1.f) * 0.5f + 0.5f;
            float zn = fminf(fmaxf(pz * inv, -1.f), 1.f) * 0.5f + 0.5f;
            float tt = fminf(fmaxf(tme[p], 0.f), 1.f);
            float c4[4] = {xn, yn, zn, tt};
            int i0[4];
            float fr[4];
#pragma unroll
            for (int cc = 0; cc < 4; ++cc) {
                float x = c4[cc] * 127.0f;
                float xf = fminf(floorf(x), 126.0f);
                i0[cc] = (int)xf;
                fr[cc] = x - xf;
            }
            const int uc[6] = {0, 0, 1, 0, 1, 2};
            const int vc[6] = {1, 2, 2, 3, 3, 3};
            __half2 g2[4];
#pragma unroll
            for (int pl = 0; pl < 6; ++pl) {
                int x0 = i0[uc[pl]], y0 = i0[vc[pl]];
                float fx = fr[uc[pl]], fy = fr[vc[pl]];
                const __half* base = ph + (size_t)pl * PLSZ + ((y0 * RPLANE + x0) << 5) + f0;
                uint4 q00 = *(const uint4*)base;
                uint4 q01 = *(const uint4*)(base + FDIM);
                uint4 q10 = *(const uint4*)(base + RPLANE * FDIM);
                uint4 q11 = *(const uint4*)(base + RPLANE * FDIM + FDIM);
                __half2 wa = __float2half2_rn((1.f - fx) * (1.f - fy));
                __half2 wb = __float2half2_rn(fx * (1.f - fy));
                __half2 wc = __float2half2_rn((1.f - fx) * fy);
                __half2 wd = __float2half2_rn(fx * fy);
                unsigned qa[4] = {q00.x, q00.y, q00.z, q00.w};
                unsigned qb[4] = {q01.x, q01.y, q01.z, q01.w};
                unsigned qc[4] = {q10.x, q10.y, q10.z, q10.w};
                unsigned qd[4] = {q11.x, q11.y, q11.z, q11.w};
#pragma unroll
                for (int i = 0; i < 4; ++i) {
                    __half2 r = __hmul2(u2h(qa[i]), wa);
                    r = __hfma2(u2h(qb[i]), wb, r);
                    r = __hfma2(u2h(qc[i]), wc, r);
                    r = __hfma2(u2h(qd[i]), wd, r);
                    g2[i] = (pl == 0) ? r : __hmul2(g2[i], r);
                }
            }
            uint4 av;
            {
                float2 v0 = __half22float2(g2[0]);
                float2 v1 = __half22float2(g2[1]);
                float2 v2 = __half22float2(g2[2]);
                float2 v3 = __half22float2(g2[3]);
                av.x = pk2(v0.x, v0.y);
                av.y = pk2(v1.x, v1.y);
                av.z = pk2(v2.x, v2.y);
                av.w = pk2(v3.x, v3.y);
            }
            act1[pt] = asfrag(av);
        }

        // ---- layer 1: wenc frags from global (L1-hot); convert -> act2 ----
        uint4 act2[2][8];
        {
            unsigned stE[2][2];
#pragma unroll
            for (int ct = 0; ct < 16; ++ct) {
                uint4 cur = *(const uint4*)(wf + (size_t)ct * 512 + lane * 8);
                float4 b4 = *(const float4*)(benc + 16 * ct + 4 * g);
                float bb[4] = {b4.x, b4.y, b4.z, b4.w};
#pragma unroll
                for (int pt = 0; pt < 2; ++pt) {
                    f32x4 z = {0.f, 0.f, 0.f, 0.f};
                    f32x4 d = __builtin_amdgcn_mfma_f32_16x16x32_bf16(asfrag(cur), act1[pt], z, 0, 0, 0);
                    float v0 = fmaxf(d[0] + bb[0], 0.f);
                    float v1 = fmaxf(d[1] + bb[1], 0.f);
                    float v2 = fmaxf(d[2] + bb[2], 0.f);
                    float v3 = fmaxf(d[3] + bb[3], 0.f);
                    unsigned Q0 = pk2(v0, v1), Q1 = pk2(v2, v3);
                    if ((ct & 1) == 0) {
                        stE[pt][0] = Q0; stE[pt][1] = Q1;
                    } else {
                        act2[pt][ct >> 1] = convD(stE[pt][0], stE[pt][1], Q0, Q1, a0, a1, sel);
                    }
                }
            }
        }

        // ---- layer 2: w1 frags from LDS; convert -> act3 ----
        uint4 act3[2][8];
        {
            unsigned stE[2][2];
#pragma unroll
            for (int ct = 0; ct < 16; ++ct) {
                uint4 w[8];
#pragma unroll
                for (int ks = 0; ks < 8; ++ks)
                    w[ks] = *(const uint4*)&wlds[(ct * 8 + ks) * 512 + lane * 8];
                float4 b4 = *(const float4*)(b1v + 16 * ct + 4 * g);
                float bb[4] = {b4.x, b4.y, b4.z, b4.w};
#pragma unroll
                for (int pt = 0; pt < 2; ++pt) {
                    f32x4 acc = {0.f, 0.f, 0.f, 0.f};
#pragma unroll
                    for (int ks = 0; ks < 8; ++ks)
                        acc = __builtin_amdgcn_mfma_f32_16x16x32_bf16(asfrag(w[ks]), asfrag(act2[pt][ks]), acc, 0, 0, 0);
                    float v0 = fmaxf(acc[0] + bb[0], 0.f);
                    float v1 = fmaxf(acc[1] + bb[1], 0.f);
                    float v2 = fmaxf(acc[2] + bb[2], 0.f);
                    float v3 = fmaxf(acc[3] + bb[3], 0.f);
                    unsigned Q0 = pk2(v0, v1), Q1 = pk2(v2, v3);
                    if ((ct & 1) == 0) {
                        stE[pt][0] = Q0; stE[pt][1] = Q1;
                    } else {
                        act3[pt][ct >> 1] = convD(stE[pt][0], stE[pt][1], Q0, Q1, a0, a1, sel);
                    }
                }
            }
        }

        // ---- layer 3: w2 frags from LDS; D[pt][outcol]; + b2 + shs -> out ----
        {
#pragma unroll
            for (int ct = 0; ct < 3; ++ct) {
                uint4 wl[8];
#pragma unroll
                for (int ks = 0; ks < 8; ++ks)
                    wl[ks] = *(const uint4*)&wlds[65536 + (ct * 8 + ks) * 512 + lane * 8];
                float bias = b2v[16 * ct + c];
#pragma unroll
                for (int pt = 0; pt < 2; ++pt) {
                    f32x4 acc = {0.f, 0.f, 0.f, 0.f};
#pragma unroll
                    for (int ks = 0; ks < 8; ++ks)
                        acc = __builtin_amdgcn_mfma_f32_16x16x32_bf16(asfrag(act3[pt][ks]), asfrag(wl[ks]), acc, 0, 0, 0);
#pragma unroll
                    for (int r = 0; r < 4; ++r) {
                        int p = p0 + pt * 16 + 4 * g + r;
                        size_t idx = (size_t)p * 48 + 16 * ct + c;
                        out[(size_t)NPTS * 8 + idx] = shs[idx] + acc[r] + bias;
                    }
                }
            }
        }
    }
}

extern "C" void kernel_launch(void* const* d_in, const int* in_sizes, int n_in,
                              void* d_out, int out_size, void* d_ws, size_t ws_size,
                              hipStream_t stream) {
    const float* rays = (const float*)d_in[0];
    const float* rot  = (const float*)d_in[1];
    const float* shs  = (const float*)d_in[3];
    const float* tme  = (const float*)d_in[5];
    const float* h_e  = (const float*)d_in[6];
    const float* spf  = (const float*)d_in[7];
    const float* tpf  = (const float*)d_in[8];
    const float* wenc = (const float*)d_in[9];
    const float* benc = (const float*)d_in[10];
    const float* w1   = (const float*)d_in[11];
    const float* b1v  = (const float*)d_in[12];
    const float* w2   = (const float*)d_in[13];
    const float* b2v  = (const float*)d_in[14];
    float* out = (float*)d_out;
    unsigned short* wf = (unsigned short*)d_ws;    // 86016 shorts of weight frags
    __half* ph = (__half*)(wf + 86016);            // 6*PLSZ fp16 plane cache (~6.3 MB)

    prep_all<<<3408, 256, 0, stream>>>(wenc, w1, w2, spf, tpf, wf, ph);
    pass_copy<<<2048, 256, 0, stream>>>(rays, rot, h_e, out);
    fused5<<<NBLK, 512, 0, stream>>>(
        rays, tme, shs, ph, wf, benc, b1v, b2v, out);
}